// Round 12
// baseline (1720.319 us; speedup 1.0000x reference)
//
#include <hip/hip_runtime.h>

typedef __attribute__((ext_vector_type(8))) _Float16 f16x8;
typedef __attribute__((ext_vector_type(4))) float f32x4;
typedef __attribute__((ext_vector_type(4))) unsigned u32x4;
typedef unsigned long long ull;

#define T_STEPS 1024
#define BATCH   128
#define FDIM    128
#define UDIM    256
#define GCOLS   1024   // 4*U
#define ROWS    16     // batch rows per group
#define HWPR    128    // h words per row (256 fp16 / 2)
#define XST     136    // x stage row stride (f16)
#define HST     264    // h stage row stride (f16)

// Protocol: tagged 64-bit words {lo32: 2 fp16 h, hi32: step tag}, double-
// buffered, relaxed agent-scope; fused wide poll. Structure: x.W MFMAs overlap
// the poll RT; in-wave gate combine; ONE barrier per step. r12 delta: x_{t+2}
// loads issued AFTER the poll loop so retries never drain HBM x latency.

__global__ __launch_bounds__(256, 1)
void lstm_scan_kernel(const float* __restrict__ xg, const float* __restrict__ Wg,
                      const float* __restrict__ Rg, const float* __restrict__ bg_,
                      float* __restrict__ outg, ull* __restrict__ hbuf)
{
    __shared__ _Float16 xs[2][ROWS][XST];
    __shared__ _Float16 hs[2][ROWS][HST];

    const int tid  = threadIdx.x;
    const int lane = tid & 63;
    const int wv   = tid >> 6;
    const int bgi  = blockIdx.x & 7;    // batch group
    const int ngi  = blockIdx.x >> 3;   // u-slice group
    const int r0   = bgi * ROWS;
    const int u0   = ngi * 32;
    const int lj   = lane & 15;         // MFMA m/n index
    const int lg   = lane >> 4;         // MFMA k-group
    const int hb   = lj >> 3;           // gate-half owner bit
    const int uc   = u0 + wv * 8 + (lj & 7);   // this lane's u column

    // ---- one-time: B fragments, in-wave mapping (wave owns 4 gates x 8 ucols)
    f16x8 bfr[2][12];
#pragma unroll
    for (int nt = 0; nt < 2; ++nt) {
        const int col = (nt * 2 + hb) * 256 + uc;
#pragma unroll
        for (int ks = 0; ks < 12; ++ks) {
            f16x8 v;
#pragma unroll
            for (int i = 0; i < 8; ++i) {
                const int k = ks * 32 + lg * 8 + i;
                const float w = (k < FDIM) ? Wg[k * GCOLS + col]
                                           : Rg[(k - FDIM) * GCOLS + col];
                v[i] = (_Float16)w;
            }
            bfr[nt][ks] = v;
        }
    }

    const float b_i = bg_[uc];
    const float b_f = bg_[256 + uc];
    const float b_g = bg_[512 + uc];
    const float b_o = bg_[768 + uc];

    const int row0 = lg * 4 + hb * 2;   // first of this lane's 2 output rows
    float cc0 = 0.f, cc1 = 0.f;

    // staging/poll roles: thread (xrow, chunk) owns 8 words of row xrow
    const int xrow = tid >> 4;
    const int xf0  = (tid & 15) * 8;    // x chunk base (8 floats / 8 fp16)
    const int hc0  = (tid & 15) * 16;   // h chunk base (16 fp16 = 8 words)
    const size_t hrd = (size_t)(r0 + xrow) * HWPR + (hc0 >> 1);
    const float* const xps = xg + (size_t)(r0 + xrow) * T_STEPS * FDIM + xf0;

    // prologue: stage x0 into xs[0]; preload x1
    {
        const f32x4 xa = *(const f32x4*)xps;
        const f32x4 xb = *(const f32x4*)(xps + 4);
        f16x8 v;
#pragma unroll
        for (int i = 0; i < 4; ++i) { v[i] = (_Float16)xa[i]; v[4 + i] = (_Float16)xb[i]; }
        *(f16x8*)&xs[0][xrow][xf0] = v;
    }
    f32x4 xn0 = *(const f32x4*)(xps + FDIM);
    f32x4 xn1 = *(const f32x4*)(xps + FDIM + 4);
    __syncthreads();

    for (int t = 0; t < T_STEPS; ++t) {
        const int p = t & 1;
        const ull* hp = hbuf + (size_t)p * BATCH * HWPR + hrd;
        const unsigned tg = (unsigned)t;

        // ---- B: issue wide poll, NO wait (poisoned tags: a skewed vmcnt can
        // only force a retry, never a false pass) ----
        u32x4 pa = {0u, 0xFFFFFFFFu, 0u, 0xFFFFFFFFu};
        u32x4 pb = pa, pc = pa, pd = pa;
        asm volatile(
            "global_load_dwordx4 %0, %4, off sc0 sc1\n\t"
            "global_load_dwordx4 %1, %4, off offset:16 sc0 sc1\n\t"
            "global_load_dwordx4 %2, %4, off offset:32 sc0 sc1\n\t"
            "global_load_dwordx4 %3, %4, off offset:48 sc0 sc1"
            : "+v"(pa), "+v"(pb), "+v"(pc), "+v"(pd)
            : "v"(hp)
            : "memory");

        // ---- A: stage x_{t+1} -> xs[p^1] (regs loaded last step) ----
        {
            f16x8 v;
#pragma unroll
            for (int i = 0; i < 4; ++i) { v[i] = (_Float16)xn0[i]; v[4 + i] = (_Float16)xn1[i]; }
            *(f16x8*)&xs[p ^ 1][xrow][xf0] = v;
        }

        // ---- C: x.W MFMAs from xs[p] — overlaps the poll round trip ----
        f32x4 a0e = {0,0,0,0}, a0o = {0,0,0,0}, a1e = {0,0,0,0}, a1o = {0,0,0,0};
#pragma unroll
        for (int ks = 0; ks < 4; ++ks) {
            const f16x8 a = *(const f16x8*)&xs[p][lj][ks * 32 + lg * 8];
            if (ks & 1) {
                a0o = __builtin_amdgcn_mfma_f32_16x16x32_f16(a, bfr[0][ks], a0o, 0, 0, 0);
                a1o = __builtin_amdgcn_mfma_f32_16x16x32_f16(a, bfr[1][ks], a1o, 0, 0, 0);
            } else {
                a0e = __builtin_amdgcn_mfma_f32_16x16x32_f16(a, bfr[0][ks], a0e, 0, 0, 0);
                a1e = __builtin_amdgcn_mfma_f32_16x16x32_f16(a, bfr[1][ks], a1e, 0, 0, 0);
            }
        }

        // ---- D: wait poll loads (nothing else in flight but publish stores),
        // check tags; retries are pure poll round-trips ----
        asm volatile("s_waitcnt vmcnt(0)" ::: "memory");
        __builtin_amdgcn_sched_barrier(0);
        while (!((pa.y == tg) & (pa.w == tg) & (pb.y == tg) & (pb.w == tg) &
                 (pc.y == tg) & (pc.w == tg) & (pd.y == tg) & (pd.w == tg))) {
            __builtin_amdgcn_s_sleep(1);
            asm volatile(
                "global_load_dwordx4 %0, %4, off sc0 sc1\n\t"
                "global_load_dwordx4 %1, %4, off offset:16 sc0 sc1\n\t"
                "global_load_dwordx4 %2, %4, off offset:32 sc0 sc1\n\t"
                "global_load_dwordx4 %3, %4, off offset:48 sc0 sc1\n\t"
                "s_waitcnt vmcnt(0)"
                : "=&v"(pa), "=&v"(pb), "=&v"(pc), "=&v"(pd)
                : "v"(hp)
                : "memory");
            __builtin_amdgcn_sched_barrier(0);
        }

        // ---- A': issue x_{t+2} loads NOW — they fly under stage-h/barrier/
        // h.R/gates/publish and next iteration's pre-poll section ----
        {
            const int tn = (t + 2 < T_STEPS) ? (t + 2) : (T_STEPS - 1);
            xn0 = *(const f32x4*)(xps + (size_t)tn * FDIM);
            xn1 = *(const f32x4*)(xps + (size_t)tn * FDIM + 4);
        }

        // ---- E: stage h -> hs[p] (fp16 payloads are the word lo32s) ----
        {
            uint4 q0, q1;
            q0.x = pa.x; q0.y = pa.z; q0.z = pb.x; q0.w = pb.z;
            q1.x = pc.x; q1.y = pc.z; q1.z = pd.x; q1.w = pd.z;
            *(uint4*)&hs[p][xrow][hc0]     = q0;
            *(uint4*)&hs[p][xrow][hc0 + 8] = q1;
        }
        __syncthreads();   // F: the ONLY barrier per step

        // ---- G: h.R MFMAs ----
#pragma unroll
        for (int ks = 4; ks < 12; ++ks) {
            const f16x8 a = *(const f16x8*)&hs[p][lj][(ks - 4) * 32 + lg * 8];
            if (ks & 1) {
                a0o = __builtin_amdgcn_mfma_f32_16x16x32_f16(a, bfr[0][ks], a0o, 0, 0, 0);
                a1o = __builtin_amdgcn_mfma_f32_16x16x32_f16(a, bfr[1][ks], a1o, 0, 0, 0);
            } else {
                a0e = __builtin_amdgcn_mfma_f32_16x16x32_f16(a, bfr[0][ks], a0e, 0, 0, 0);
                a1e = __builtin_amdgcn_mfma_f32_16x16x32_f16(a, bfr[1][ks], a1e, 0, 0, 0);
            }
        }
        const f32x4 z0 = a0e + a0o;   // gates i,f
        const f32x4 z1 = a1e + a1o;   // gates g,o

        // ---- H: in-wave gate combine (partner lane^8 holds the other gate)
        float s0[4], s1[4];
#pragma unroll
        for (int e = 0; e < 4; ++e) {
            s0[e] = __shfl_xor(z0[e], 8);
            s1[e] = __shfl_xor(z1[e], 8);
        }
        float zi0 = hb ? s0[2] : z0[0];
        float zi1 = hb ? s0[3] : z0[1];
        float zf0 = hb ? z0[2] : s0[0];
        float zf1 = hb ? z0[3] : s0[1];
        float zg0 = hb ? s1[2] : z1[0];
        float zg1 = hb ? s1[3] : z1[1];
        float zo0 = hb ? z1[2] : s1[0];
        float zo1 = hb ? z1[3] : s1[1];

        zi0 += b_i; zi1 += b_i; zf0 += b_f; zf1 += b_f;
        zg0 += b_g; zg1 += b_g; zo0 += b_o; zo1 += b_o;

        const float i0 = 1.f / (1.f + __expf(-zi0));
        const float f0 = 1.f / (1.f + __expf(-zf0));
        const float o0 = 1.f / (1.f + __expf(-zo0));
        const float i1 = 1.f / (1.f + __expf(-zi1));
        const float f1 = 1.f / (1.f + __expf(-zf1));
        const float o1 = 1.f / (1.f + __expf(-zo1));
        cc0 = f0 * cc0 + i0 * zg0;     // g is LINEAR (activation=None)
        cc1 = f1 * cc1 + i1 * zg1;
        const float h0v = o0 * cc0;    // h = o * c (no tanh on cell)
        const float h1v = o1 * cc1;

        // ---- I: publish / output ----
        if (t == T_STEPS - 1) {
            float* op = outg + (size_t)(r0 + row0) * UDIM + uc;
            op[0]    = tanhf(h0v);     // post-hoc tanh on last h
            op[UDIM] = tanhf(h1v);
        } else {
            const float n0 = __shfl_xor(h0v, 1);
            const float n1 = __shfl_xor(h1v, 1);
            if (!(lj & 1)) {
                union { _Float16 h[2]; unsigned lo; } qa, qb;
                qa.h[0] = (_Float16)h0v; qa.h[1] = (_Float16)n0;
                qb.h[0] = (_Float16)h1v; qb.h[1] = (_Float16)n1;
                const ull tagw = (ull)(unsigned)(t + 1) << 32;
                ull* hw = hbuf + (size_t)(p ^ 1) * BATCH * HWPR
                          + (size_t)(r0 + row0) * HWPR + (uc >> 1);
                __hip_atomic_store(hw,        tagw | qa.lo,
                                   __ATOMIC_RELAXED, __HIP_MEMORY_SCOPE_AGENT);
                __hip_atomic_store(hw + HWPR, tagw | qb.lo,
                                   __ATOMIC_RELAXED, __HIP_MEMORY_SCOPE_AGENT);
            }
        }
    }
}

extern "C" void kernel_launch(void* const* d_in, const int* in_sizes, int n_in,
                              void* d_out, int out_size, void* d_ws, size_t ws_size,
                              hipStream_t stream) {
    const float* x = (const float*)d_in[0];   // [128,1024,128]
    const float* W = (const float*)d_in[1];   // [128,1024]
    const float* R = (const float*)d_in[2];   // [256,1024]
    const float* b = (const float*)d_in[3];   // [1024]
    float* out = (float*)d_out;               // [128,256]

    ull* hbuf = (ull*)d_ws;                   // [2][128][128] tagged words

    // zero tags every launch (tag 0 == "h ready for step 0", h == 0)
    const size_t clr = (size_t)2 * BATCH * HWPR * sizeof(ull);
    hipMemsetAsync(d_ws, 0, clr, stream);

    hipLaunchKernelGGL(lstm_scan_kernel, dim3(64), dim3(256), 0, stream,
                       x, W, R, b, out, hbuf);
}